// Round 5
// baseline (91.201 us; speedup 1.0000x reference)
//
#include <hip/hip_runtime.h>
#include <math.h>

#define MM 2049
#define BB 16
#define NN 512
#define JH 1025           // half-spectrum (j = 0..1024)
#define JP 1040           // padded row stride for PSp (float2 units)
#define SZ 8              // s-pair-chunk split in phase 1
#define PCH 128           // pairs per chunk: 8*128 = 1024 pairs (s=1..1024)
#define JCH 5             // j-chunks of 256 (5*256 >= 1025)
// k_dft2g v3 decomposition: 32 t per block (2 chains/lane) x 16 j-splits
#define TB 32             // t-values per block (2 per lane, sharing ds_read)
#define JS 16             // j-splits per t (shfl-reduced)
#define JSL 65            // j per split: 16*65 = 1040 >= 1025
#define NTC 33            // t-chunks: 33*32 = 1056 >= 1025

static constexpr double D_TWO_PI    = 6.283185307179586476925286766559;
static constexpr double D_STEP      = D_TWO_PI / 2049.0;
static constexpr float  F_TWO_PI    = 6.28318530717958647692f;
static constexpr float  INV_4TAU    = 83333.33333333333f;   // 1/(4*3e-6)
static constexpr float  PI_OVER_TAU = 1047197.5511965977f;  // pi/tau
static constexpr float  TWO_TAU     = 6.0e-6f;              // 2*tau
static constexpr float  INV_2PI     = 0.15915494309189533f;
static constexpr float  INV_M       = 1.0f / 2049.0f;
static constexpr float  WINF        = 8.0f;

// ---------------------------------------------------------------------------
// Round-4 post-mortem (A/B across rounds 3/4, same dispatch structure):
// k_dft2g v2 is still ~25 us. Its three costs all scale with decomposition
// redundancy (NTC x per-block work): per-CU LDS b128 traffic in the j-sum,
// 65x re-staging of PSp (68 MB), and 1040 blocks each scanning all 512
// points in the gather. v3: TB 16->32, NTC 65->33; each lane runs TWO
// t-chains (t, t+16) off ONE ds_read_b128 -> LDS reads/CU ~4x down,
// staging and windowcalc 2x down, chain length unchanged (65, numerics
// identical). 528 blocks = ~2/CU, 8 waves/CU.
// ---------------------------------------------------------------------------

// ------------------------------------- spread + DFT1 (s-symmetry folded) ----
__global__ void k_sdft1(const float* __restrict__ x, float2* __restrict__ PSp,
                        float* __restrict__ out) {
    __shared__ float  LA[PCH];
    __shared__ float  LB[PCH];
    __shared__ float2 SD[PCH];   // {sum, diff}
    __shared__ float  Lz;        // red[0] (z==0 only)
    const int b  = blockIdx.y;
    const int z  = blockIdx.z;
    const int a0 = 1 + PCH * z;            // A = [a0, a0+PCH-1]  subset of [1,1024]
    const int b0 = 2049 - PCH * (z + 1);   // B = [b0, b0+PCH-1]  mirror (2049-s)
    // zero the output slice for batch b (k_dft2g accumulates with atomics);
    // visible to k_dft2g across the dispatch boundary.
    if (blockIdx.x == 0 && z == 0) {
        for (int i = threadIdx.x; i < NN * 2; i += 256) out[b * NN * 2 + i] = 0.0f;
    }
    for (int i = threadIdx.x; i < PCH; i += 256) { LA[i] = 0.0f; LB[i] = 0.0f; }
    if (threadIdx.x == 0) Lz = 0.0f;
    __syncthreads();
    for (int n = threadIdx.x; n < NN; n += 256) {
        float xv = x[b * NN + n];
        float xa = xv * F_TWO_PI;
        float p  = xv * (float)MM;
        int m0 = (int)ceilf(p - WINF);  if (m0 < 0) m0 = 0;
        int m1 = (int)floorf(p + WINF); if (m1 > MM - 1) m1 = MM - 1;
        bool hitA = (m1 >= a0) && (m0 <= a0 + PCH - 1);
        bool hitB = (m1 >= b0) && (m0 <= b0 + PCH - 1);
        bool hit0 = (z == 0) && (m0 == 0);
        if (!(hitA || hitB || hit0)) continue;
        for (int m = m0; m <= m1; ++m) {
            float xg = (float)((double)m * D_STEP);
            float d  = xa - xg;
            float g  = expf(-(d * d) * INV_4TAU);
            unsigned ia = (unsigned)(m - a0);
            unsigned ib = (unsigned)(m - b0);
            if (ia < PCH) atomicAdd(&LA[ia], g);
            if (ib < PCH) atomicAdd(&LB[ib], g);
            if (hit0 && m == 0) atomicAdd(&Lz, g);
        }
    }
    __syncthreads();
    // fold: pair of s=a0+i is s'=2049-a0-i = b0 + (PCH-1-i)
    for (int i = threadIdx.x; i < PCH; i += 256) {
        float ra = LA[i], rb = LB[PCH - 1 - i];
        SD[i] = make_float2(ra + rb, ra - rb);
    }
    __syncthreads();
    const int j = blockIdx.x * 256 + threadIdx.x;
    if (j >= JH) return;
    float ct, st;   // rotation step e^{i*2pi*j/M}
    { float ang = (float)((double)j * D_STEP); __sincosf(ang, &st, &ct); }
    float c, s;     // phase at s = a0
    { int r0 = (j * a0) % MM; float ph = (float)((double)r0 * D_STEP); __sincosf(ph, &s, &c); }
    float accc = 0.0f, accs = 0.0f;
    #pragma unroll 4
    for (int i = 0; i < PCH; ++i) {
        float2 sd = SD[i];                  // LDS broadcast b64
        accc = fmaf(sd.x, c, accc);
        accs = fmaf(sd.y, s, accs);
        float t1 = s * st, t2 = s * ct;
        float cn = fmaf(c, ct, -t1);
        float sn = fmaf(c, st,  t2);
        c = cn; s = sn;
    }
    if (z == 0) accc += Lz;                 // s = 0 term (cos=1, sin=0)
    PSp[((size_t)b * SZ + z) * JP + j] = make_float2(accc, accs);
}

// --------------------- mid + DFT2 (full j-sum per t-chunk) + fused gather ----
// Block (tc, b): t in [tc*32, tc*32+31]. Lane (q, tt) runs TWO rotation
// chains tA = t0+tt, tB = t0+16+tt over j in [q*65, q*65+64], sharing each
// lab[i] ds_read. Partials reduced over q with in-wave shfl_xor. Final irf
// values for the block's m-ownership {t} u {M-t} land in LDS; the block then
// gathers every point of batch b whose window overlaps and atomicAdds out.
__global__ __launch_bounds__(256)
void k_dft2g(const float2* __restrict__ PSp,
             const float* __restrict__ mRe0, const float* __restrict__ mIm0,
             const float* __restrict__ mRe1, const float* __restrict__ mIm1,
             const float* __restrict__ x, float* __restrict__ out) {
    __shared__ float4 lab[JH];       // 16400 B: {A0, A1, Bd0, Bd1} per j
    __shared__ float2 irfL[TB];      // irf at m = t0+i       (ch0, ch1)
    __shared__ float2 irfH[TB];      // irf at m = MM-(t0+i)  (ch0, ch1)
    const int tc  = blockIdx.x;      // 0..32
    const int b   = blockIdx.y;      // 0..15
    const int t0  = tc * TB;
    const int tid = threadIdx.x;

    // stage weighted spectral coefficients (fold the 8 s-partials, apply
    // deconv^2 * mult channel-swapped) for ALL j
    for (int i = tid; i < JH; i += 256) {
        const int j = i;
        float cs = 0.0f, sn = 0.0f;
        const float2* base = PSp + (size_t)b * SZ * JP + j;
        #pragma unroll
        for (int z = 0; z < SZ; ++z) {
            float2 ps = base[(size_t)z * JP];
            cs += ps.x; sn += ps.y;
        }
        const int msh = j + 1024;
        const float jf = (float)j;
        const float d2 = PI_OVER_TAU * expf(jf * jf * TWO_TAU);
        const float fac = (j == 0) ? 1.0f : 2.0f;
        const float sc = INV_2PI * d2 * fac;
        float4 v;
        v.x =  sc * mRe1[msh] * cs;   // A  ch0 (channel swap from ifftshift)
        v.y =  sc * mRe0[msh] * cs;   // A  ch1
        v.z = -sc * mIm1[msh] * sn;   // Bd ch0
        v.w = -sc * mIm0[msh] * sn;   // Bd ch1
        lab[i] = v;
    }
    __syncthreads();

    // per-t j-sum: 16-way lane-split, 2 t-chains per lane sharing the ds_read
    {
        const int q  = tid & (JS - 1);   // j-sixteenth 0..15 (lane bits 0..3)
        const int tt = tid >> 4;         // 0..15
        const int tA = t0 + tt;
        const int tB = t0 + JS + tt;
        const int j0 = q * JSL;
        const int j1 = min(j0 + JSL, JH);
        float ctA, stA, ctB, stB;        // rotation steps e^{i*2pi*t/M}
        { float a = (float)((double)tA * D_STEP); __sincosf(a, &stA, &ctA); }
        { float a = (float)((double)tB * D_STEP); __sincosf(a, &stB, &ctB); }
        float cA, sA, cB, sB;            // phases at j = j0
        { int r0 = (tA * j0) % MM; float ph = (float)((double)r0 * D_STEP); __sincosf(ph, &sA, &cA); }
        { int r0 = (tB * j0) % MM; float ph = (float)((double)r0 * D_STEP); __sincosf(ph, &sB, &cB); }
        float EA0 = 0.0f, OA0 = 0.0f, EA1 = 0.0f, OA1 = 0.0f;
        float EB0 = 0.0f, OB0 = 0.0f, EB1 = 0.0f, OB1 = 0.0f;
        #pragma unroll 4
        for (int i = j0; i < j1; ++i) {
            float4 v = lab[i];           // one b128 feeds both chains
            EA0 = fmaf(v.x, cA, EA0);
            OA0 = fmaf(v.z, sA, OA0);
            EA1 = fmaf(v.y, cA, EA1);
            OA1 = fmaf(v.w, sA, OA1);
            EB0 = fmaf(v.x, cB, EB0);
            OB0 = fmaf(v.z, sB, OB0);
            EB1 = fmaf(v.y, cB, EB1);
            OB1 = fmaf(v.w, sB, OB1);
            { float t1 = sA * stA, t2 = sA * ctA;
              float cn = fmaf(cA, ctA, -t1);
              float sn = fmaf(cA, stA,  t2);
              cA = cn; sA = sn; }
            { float t1 = sB * stB, t2 = sB * ctB;
              float cn = fmaf(cB, ctB, -t1);
              float sn = fmaf(cB, stB,  t2);
              cB = cn; sB = sn; }
        }
        // reduce the 16 j-split partials (lanes differ only in bits 0..3)
        #pragma unroll
        for (int off = 8; off > 0; off >>= 1) {
            EA0 += __shfl_xor(EA0, off);
            OA0 += __shfl_xor(OA0, off);
            EA1 += __shfl_xor(EA1, off);
            OA1 += __shfl_xor(OA1, off);
            EB0 += __shfl_xor(EB0, off);
            OB0 += __shfl_xor(OB0, off);
            EB1 += __shfl_xor(EB1, off);
            OB1 += __shfl_xor(OB1, off);
        }
        if (q == 0) {
            if (tA < JH) {
                irfL[tt] = make_float2((EA0 - OA0) * INV_M, (EA1 - OA1) * INV_M);
                irfH[tt] = make_float2((EA0 + OA0) * INV_M, (EA1 + OA1) * INV_M);
            }
            if (tB < JH) {
                irfL[JS + tt] = make_float2((EB0 - OB0) * INV_M, (EB1 - OB1) * INV_M);
                irfH[JS + tt] = make_float2((EB0 + OB0) * INV_M, (EB1 + OB1) * INV_M);
            }
        }
    }
    __syncthreads();

    // fused gather over this block's m-ownership
    const int L0 = t0;
    const int L1 = min(t0 + TB, JH) - 1;                // m = t range [L0, L1]
    const int H0 = MM - L1, H1 = MM - max(t0, 1);       // m = MM - t, t >= 1
    for (int n = tid; n < NN; n += 256) {
        const int p = b * NN + n;
        float xv = x[p];
        float xa = xv * F_TWO_PI;
        float pp = xv * (float)MM;
        int m0 = (int)ceilf(pp - WINF);  if (m0 < 0) m0 = 0;
        int m1 = (int)floorf(pp + WINF); if (m1 > MM - 1) m1 = MM - 1;
        float a0 = 0.0f, a1 = 0.0f;
        int lo = max(m0, L0), hi = min(m1, L1);
        for (int m = lo; m <= hi; ++m) {
            float xg = (float)((double)m * D_STEP);
            float d  = xa - xg;
            float g  = expf(-(d * d) * INV_4TAU);
            float2 v = irfL[m - L0];
            a0 = fmaf(g, v.x, a0);
            a1 = fmaf(g, v.y, a1);
        }
        int lo2 = max(m0, H0), hi2 = min(m1, H1);
        for (int m = lo2; m <= hi2; ++m) {
            float xg = (float)((double)m * D_STEP);
            float d  = xa - xg;
            float g  = expf(-(d * d) * INV_4TAU);
            float2 v = irfH[(MM - m) - t0];
            a0 = fmaf(g, v.x, a0);
            a1 = fmaf(g, v.y, a1);
        }
        if ((hi >= lo) || (hi2 >= lo2)) {
            atomicAdd(&out[p * 2 + 0], a0 * INV_M);
            atomicAdd(&out[p * 2 + 1], a1 * INV_M);
        }
    }
}

// ---------------------------------------------------------------- launch ----
extern "C" void kernel_launch(void* const* d_in, const int* in_sizes, int n_in,
                              void* d_out, int out_size, void* d_ws, size_t ws_size,
                              hipStream_t stream) {
    const float* x    = (const float*)d_in[0];
    const float* mRe0 = (const float*)d_in[1];
    const float* mIm0 = (const float*)d_in[2];
    const float* mRe1 = (const float*)d_in[3];
    const float* mIm1 = (const float*)d_in[4];
    float* out = (float*)d_out;

    float2* PSp = (float2*)d_ws;    // [BB][SZ][JP] float2

    k_sdft1<<<dim3(JCH, BB, SZ), 256, 0, stream>>>(x, PSp, out);
    k_dft2g<<<dim3(NTC, BB), 256, 0, stream>>>(PSp, mRe0, mIm0, mRe1, mIm1, x, out);
}